// Round 1
// baseline (104.823 us; speedup 1.0000x reference)
//
#include <hip/hip_runtime.h>
#include <math.h>

// ---- config (mirrors reference) ----
#define SR_D        44100.0
#define N_SAMPLES   65536
#define BVOICES     256
#define TWO_PI_F    6.28318530717958647692f
#define TWO_PI_D    6.28318530717958647692528676655900577

#define TPB 256      // threads per block
#define SPT 16       // samples per thread (4x float4 stores)
#define SPB (TPB*SPT)           // 4096 samples per block
#define BLOCKS_PER_ROW (N_SAMPLES / SPB)   // 16

struct VoiceD {
    double Cc;      // phase + K4*cos(a-h)          [revolutions]
    double c1;      // f0/SR                        [rev/sample]
    double th0rev;  // (a+h)/(2pi): theta at n=0    [rev]
    double fmrev;   // fm/SR: theta step per sample [rev/sample]
    double pam0;    // phase_am                     [rev]
    double amrev;   // am_hz/SR                     [rev/sample]
};
struct VoiceF {
    float c1f;      // f0/SR
    float fmrevf;   // fm/SR
    float K4f;      // c1*mi_fm/(2 sin h)
    float miamf;    // mi_am
    float amrevf;   // am_hz/SR
    float pad0, pad1, pad2;
};

__device__ VoiceD g_vd[BVOICES];
__device__ VoiceF g_vf[BVOICES];

// One-block setup: per-voice constant precompute (fp64; params in f32 to match
// the reference's f32 exp2 path, then promoted).
__global__ void amfm_setup_kernel(const float* __restrict__ th_am,
                                  const float* __restrict__ th_fm,
                                  const float* __restrict__ ph,
                                  const float* __restrict__ ph_am,
                                  const float* __restrict__ ph_fm,
                                  const float* __restrict__ u_am_mi,
                                  const float* __restrict__ u_fm_hz,
                                  const float* __restrict__ u_f0_hz) {
    int i = threadIdx.x;
    if (i >= BVOICES) return;

    // Match reference f32 math for the parameter mapping:
    // am_hz = exp2(theta_am * (log2 8 - log2 .5) + log2 .5) = exp2(4*t - 1)
    float am_hz = exp2f(th_am[i] * 4.0f - 1.0f);
    float mi_am = u_am_mi[i];                 // * (1-0) + 0
    float mi_fm = th_fm[i];                   // * (1-0) + 0
    float fm_hz = exp2f(u_fm_hz[i] * 4.0f - 1.0f);
    const double l2lo = log2(32.7);
    const double l2hi = log2(523.25);
    float f0_hz = exp2f(u_f0_hz[i] * (float)(l2hi - l2lo) + (float)l2lo);

    // Closed-form cumsum constants (fp64):
    // arg_rev[n] = Cc + c1*(n+1) - K4*cos(a + (2n+1)h),  h = pi*fm/SR
    double c1  = (double)f0_hz / SR_D;
    double h   = M_PI * (double)fm_hz / SR_D;       // fm_hz >= 0.5 -> h > 0
    double K4  = c1 * (double)mi_fm / (2.0 * sin(h));
    double a   = TWO_PI_D * (double)ph_fm[i];
    double Cc  = (double)ph[i] + K4 * cos(a - h);

    VoiceD d;
    d.Cc     = Cc;
    d.c1     = c1;
    d.th0rev = (a + h) / TWO_PI_D;
    d.fmrev  = (double)fm_hz / SR_D;
    d.pam0   = (double)ph_am[i];
    d.amrev  = (double)am_hz / SR_D;
    g_vd[i] = d;

    VoiceF f;
    f.c1f    = (float)c1;
    f.fmrevf = (float)d.fmrev;
    f.K4f    = (float)K4;
    f.miamf  = mi_am;
    f.amrevf = (float)d.amrev;
    f.pad0 = f.pad1 = f.pad2 = 0.0f;
    g_vf[i] = f;
}

__global__ void __launch_bounds__(TPB)
amfm_synth_kernel(float* __restrict__ out) {
    const int bid  = blockIdx.x;
    const int row  = bid >> 4;                  // /BLOCKS_PER_ROW
    const int col0 = (bid & (BLOCKS_PER_ROW - 1)) * SPB;
    const int n0   = col0 + threadIdx.x * SPT;

    const VoiceD d = g_vd[row];
    const VoiceF f = g_vf[row];

    // fp64 chunk bases, reduced to [0,1) revolutions, then fp32 inner loop.
    double db = d.Cc + d.c1 * (double)(n0 + 1);
    float carb = (float)(db - floor(db));
    double tb = d.th0rev + d.fmrev * (double)n0;
    float thb = (float)(tb - floor(tb));
    double ab = d.pam0 + d.amrev * (double)n0;
    float amb = (float)(ab - floor(ab));

    float res[SPT];
#pragma unroll
    for (int k = 0; k < SPT; ++k) {
        // FM-modulated carrier phase (revolutions)
        float lr = fmaf(f.c1f, (float)k, carb);
        float th = fmaf(f.fmrevf, (float)k, thb);
        th -= floorf(th);
        float cv = __cosf(TWO_PI_F * th);
        float ar = fmaf(-f.K4f, cv, lr);
        ar -= floorf(ar);
        float s = __sinf(TWO_PI_F * ar);
        // AM envelope
        float am = fmaf(f.amrevf, (float)k, amb);
        am -= floorf(am);
        float av = __sinf(TWO_PI_F * am);
        res[k] = 0.5f * s * fmaf(f.miamf, av, 1.0f);
    }

    float* op = out + (size_t)row * N_SAMPLES + n0;
#pragma unroll
    for (int j = 0; j < SPT / 4; ++j) {
        reinterpret_cast<float4*>(op)[j] =
            make_float4(res[4*j], res[4*j+1], res[4*j+2], res[4*j+3]);
    }
}

extern "C" void kernel_launch(void* const* d_in, const int* in_sizes, int n_in,
                              void* d_out, int out_size, void* d_ws, size_t ws_size,
                              hipStream_t stream) {
    const float* th_am  = (const float*)d_in[0];
    const float* th_fm  = (const float*)d_in[1];
    const float* ph     = (const float*)d_in[2];
    const float* ph_am  = (const float*)d_in[3];
    const float* ph_fm  = (const float*)d_in[4];
    const float* u_am   = (const float*)d_in[5];
    const float* u_fm   = (const float*)d_in[6];
    const float* u_f0   = (const float*)d_in[7];
    float* out = (float*)d_out;

    amfm_setup_kernel<<<1, BVOICES, 0, stream>>>(th_am, th_fm, ph, ph_am, ph_fm,
                                                 u_am, u_fm, u_f0);
    const int nblocks = BVOICES * BLOCKS_PER_ROW;   // 4096
    amfm_synth_kernel<<<nblocks, TPB, 0, stream>>>(out);
}

// Round 8
// 95.944 us; speedup vs baseline: 1.0926x; 1.0926x over previous
//
#include <hip/hip_runtime.h>
#include <math.h>

// ---- config (mirrors reference) ----
#define SR_D        44100.0
#define N_SAMPLES   65536
#define BVOICES     256
#define TWO_PI_F    6.28318530717958647692f
#define TWO_PI_D    6.28318530717958647692528676655900577

#define TPB 256                      // threads per block
#define GROUPS 4                     // float4 groups per thread
#define GROUP_STRIDE (TPB * 4)       // 1024 samples between groups
#define SPB (GROUP_STRIDE * GROUPS)  // 4096 samples per block
#define BLOCKS_PER_ROW (N_SAMPLES / SPB)   // 16

struct VoiceD {
    double Cc;      // phase + K4*cos(a-h)          [revolutions]
    double c1;      // f0/SR                        [rev/sample]
    double th0rev;  // (a+h)/(2pi): theta at n=0    [rev]
    double fmrev;   // fm/SR                        [rev/sample]
    double pam0;    // phase_am                     [rev]
    double amrev;   // am_hz/SR                     [rev/sample]
};
struct VoiceF {
    float c1f;      // f0/SR                (per-sample step)
    float fmrevf;   // fm/SR
    float amrevf;   // am_hz/SR
    float K4f;      // c1*mi_fm/(2 sin h)
    float halfmi;   // 0.5*mi_am
    float c1k;      // fract(1024*c1)       (per-group step)
    float fmk;      // fract(1024*fmrev)
    float amk;      // fract(1024*amrev)
};

__device__ VoiceD g_vd[BVOICES];
__device__ VoiceF g_vf[BVOICES];

__device__ __forceinline__ float fractf(float x) { return x - floorf(x); }

// One-block setup: per-voice constants (fp64; param mapping in f32 to match
// the reference's f32 exp2 path, then promoted).
// NOTE: log2 bounds are computed by the compiler/libm — round-2..6 regression
// was hand-typed literals off by +2e-4 (=> f0 bias => 0.55 absmax drift).
__global__ void amfm_setup_kernel(const float* __restrict__ th_am,
                                  const float* __restrict__ th_fm,
                                  const float* __restrict__ ph,
                                  const float* __restrict__ ph_am,
                                  const float* __restrict__ ph_fm,
                                  const float* __restrict__ u_am_mi,
                                  const float* __restrict__ u_fm_hz,
                                  const float* __restrict__ u_f0_hz) {
    int i = threadIdx.x;
    if (i >= BVOICES) return;

    float am_hz = exp2f(th_am[i] * 4.0f - 1.0f);      // exp2(t*(3-(-1)) + (-1))
    float mi_am = u_am_mi[i];
    float mi_fm = th_fm[i];
    float fm_hz = exp2f(u_fm_hz[i] * 4.0f - 1.0f);
    const double l2lo = log2(32.7);
    const double l2hi = log2(523.25);
    float f0_hz = exp2f(u_f0_hz[i] * (float)(l2hi - l2lo) + (float)l2lo);

    // Closed-form cumsum (exact Dirichlet identity), all in revolutions:
    // arg_rev[n] = Cc + c1*(n+1) - K4*cos(2pi*(th0rev + fmrev*n)),  h = pi*fm/SR
    double c1  = (double)f0_hz / SR_D;
    double h   = M_PI * (double)fm_hz / SR_D;
    double K4  = c1 * (double)mi_fm / (2.0 * sin(h));
    double a   = TWO_PI_D * (double)ph_fm[i];
    double Cc  = (double)ph[i] + K4 * cos(a - h);

    VoiceD d;
    d.Cc     = Cc;
    d.c1     = c1;
    d.th0rev = (a + h) / TWO_PI_D;
    d.fmrev  = (double)fm_hz / SR_D;
    d.pam0   = (double)ph_am[i];
    d.amrev  = (double)am_hz / SR_D;
    g_vd[i] = d;

    VoiceF f;
    f.c1f    = (float)c1;
    f.fmrevf = (float)d.fmrev;
    f.amrevf = (float)d.amrev;
    f.K4f    = (float)K4;
    f.halfmi = 0.5f * mi_am;
    double g = (double)GROUP_STRIDE;
    f.c1k    = (float)(g * c1      - floor(g * c1));
    f.fmk    = (float)(g * d.fmrev - floor(g * d.fmrev));
    f.amk    = (float)(g * d.amrev - floor(g * d.amrev));
    g_vf[i] = f;
}

__global__ void __launch_bounds__(TPB)
amfm_synth_kernel(float* __restrict__ out) {
    const int bid  = blockIdx.x;
    const int row  = bid >> 4;                    // / BLOCKS_PER_ROW
    const int col0 = (bid & (BLOCKS_PER_ROW - 1)) * SPB;
    const int t4   = threadIdx.x * 4;
    const int n0   = col0 + t4;                   // group-0 start sample

    const VoiceD d = g_vd[row];
    const VoiceF f = g_vf[row];

    // fp64 group-0 bases, reduced to [0,1) revolutions.
    double db = d.Cc + d.c1 * (double)(n0 + 1);
    float carb = (float)(db - floor(db));
    double tb = d.th0rev + d.fmrev * (double)n0;
    float thb = (float)(tb - floor(tb));
    double ab = d.pam0 + d.amrev * (double)n0;
    float amb = (float)(ab - floor(ab));

    float* op = out + (size_t)row * N_SAMPLES + n0;

#pragma unroll
    for (int j = 0; j < GROUPS; ++j) {
        float r[4];
#pragma unroll
        for (int k = 0; k < 4; ++k) {
            const float kk = (float)k;
            // FM oscillator: cos(2pi*theta), theta in revolutions
            float th = fractf(fmaf(f.fmrevf, kk, thb));
            float cv = __cosf(TWO_PI_F * th);
            // carrier phase (closed-form cumsum), revolutions
            float ar = fmaf(-f.K4f, cv, fmaf(f.c1f, kk, carb));
            ar = fractf(ar);
            float s = __sinf(TWO_PI_F * ar);
            // AM envelope
            float am = fractf(fmaf(f.amrevf, kk, amb));
            float av = __sinf(TWO_PI_F * am);
            r[k] = s * fmaf(f.halfmi, av, 0.5f);   // 0.5*s*(1+mi*av)
        }
        reinterpret_cast<float4*>(op + j * GROUP_STRIDE)[0] =
            make_float4(r[0], r[1], r[2], r[3]);
        // advance group bases by fract(1024*step), stay in [0,1)
        carb = fractf(carb + f.c1k);
        thb  = fractf(thb + f.fmk);
        amb  = fractf(amb + f.amk);
    }
}

extern "C" void kernel_launch(void* const* d_in, const int* in_sizes, int n_in,
                              void* d_out, int out_size, void* d_ws, size_t ws_size,
                              hipStream_t stream) {
    const float* th_am  = (const float*)d_in[0];
    const float* th_fm  = (const float*)d_in[1];
    const float* ph     = (const float*)d_in[2];
    const float* ph_am  = (const float*)d_in[3];
    const float* ph_fm  = (const float*)d_in[4];
    const float* u_am   = (const float*)d_in[5];
    const float* u_fm   = (const float*)d_in[6];
    const float* u_f0   = (const float*)d_in[7];
    float* out = (float*)d_out;

    amfm_setup_kernel<<<1, BVOICES, 0, stream>>>(th_am, th_fm, ph, ph_am, ph_fm,
                                                 u_am, u_fm, u_f0);
    const int nblocks = BVOICES * BLOCKS_PER_ROW;   // 4096
    amfm_synth_kernel<<<nblocks, TPB, 0, stream>>>(out);
}